// Round 1
// 827.387 us; speedup vs baseline: 1.1201x; 1.1201x over previous
//
#include <hip/hip_runtime.h>
#include <hip/hip_bf16.h>

#define NN 100000
#define NE 600000
#define DD 128
#define NBLK 98   // ceil(NN/1024)

typedef __attribute__((ext_vector_type(8))) short short8_t;
typedef __attribute__((ext_vector_type(4))) float float4_t;

__device__ __forceinline__ unsigned short f2bf(float f) {
    union { float f; unsigned int i; } v; v.f = f;
    unsigned int r = v.i + 0x7fffu + ((v.i >> 16) & 1u);
    return (unsigned short)(r >> 16);
}

// ---------- counting-sort infrastructure ----------

__global__ __launch_bounds__(256) void k_hist(
    const int* __restrict__ src, const int* __restrict__ dst,
    int* __restrict__ cnt_o, int* __restrict__ cnt_i)
{
    int e = blockIdx.x * 256 + threadIdx.x;
    if (e < NE) {
        atomicAdd(&cnt_o[dst[e]], 1);
        atomicAdd(&cnt_i[src[e]], 1);
    }
}

__global__ __launch_bounds__(256) void k_scanA(
    const int* __restrict__ cnt_o, const int* __restrict__ cnt_i,
    int* __restrict__ ptr_o, int* __restrict__ ptr_i, int* __restrict__ bsum)
{
    __shared__ int sh[256];
    const int* cnt = blockIdx.y ? cnt_i : cnt_o;
    int* ptr       = blockIdx.y ? ptr_i : ptr_o;
    int t = threadIdx.x;
    int base = blockIdx.x * 1024 + t * 4;
    int c[4];
    #pragma unroll
    for (int j = 0; j < 4; j++) c[j] = (base + j < NN) ? cnt[base + j] : 0;
    int s = c[0] + c[1] + c[2] + c[3];
    sh[t] = s;
    __syncthreads();
    for (int off = 1; off < 256; off <<= 1) {
        int v = (t >= off) ? sh[t - off] : 0;
        __syncthreads();
        sh[t] += v;
        __syncthreads();
    }
    int excl = sh[t] - s;
    int e0 = excl, e1 = e0 + c[0], e2 = e1 + c[1], e3 = e2 + c[2];
    if (base     < NN) ptr[base]     = e0;
    if (base + 1 < NN) ptr[base + 1] = e1;
    if (base + 2 < NN) ptr[base + 2] = e2;
    if (base + 3 < NN) ptr[base + 3] = e3;
    if (t == 255) bsum[blockIdx.y * 128 + blockIdx.x] = sh[255];
}

__global__ __launch_bounds__(128) void k_scanB(int* __restrict__ bsum)
{
    __shared__ int sh[128];
    int t = threadIdx.x;
    int* b = bsum + blockIdx.y * 128;
    int v = (t < NBLK) ? b[t] : 0;
    sh[t] = v;
    __syncthreads();
    for (int off = 1; off < 128; off <<= 1) {
        int u = (t >= off) ? sh[t - off] : 0;
        __syncthreads();
        sh[t] += u;
        __syncthreads();
    }
    b[t] = sh[t] - v;   // exclusive
}

__global__ __launch_bounds__(256) void k_scanC(
    int* __restrict__ ptr_o, int* __restrict__ ptr_i, const int* __restrict__ bsum)
{
    int* ptr = blockIdx.y ? ptr_i : ptr_o;
    int off = bsum[blockIdx.y * 128 + blockIdx.x];
    int base = blockIdx.x * 1024 + threadIdx.x * 4;
    #pragma unroll
    for (int j = 0; j < 4; j++)
        if (base + j < NN) ptr[base + j] += off;
    if (blockIdx.x == 0 && threadIdx.x == 0) ptr[NN] = NE;
}

// Adjacency entries now carry (edge_id, other_endpoint) so k_gather has no
// dependent index chase: list -> row loads directly.
__global__ __launch_bounds__(256) void k_fill(
    const int* __restrict__ src, const int* __restrict__ dst,
    const int* __restrict__ ptr_o, const int* __restrict__ ptr_i,
    int* __restrict__ cur_o, int* __restrict__ cur_i,
    int2* __restrict__ list_o, int2* __restrict__ list_i)
{
    int e = blockIdx.x * 256 + threadIdx.x;
    if (e < NE) {
        int s = src[e], t = dst[e];
        int p = atomicAdd(&cur_o[t], 1);
        list_o[ptr_o[t] + p] = make_int2(e, s);
        int q = atomicAdd(&cur_i[s], 1);
        list_i[ptr_i[s] + q] = make_int2(e, t);
    }
}

// ---------- gather: one wave per (node, direction) ----------
// Latency-optimized: the wave's entire (e,u) adjacency segment is prefetched
// in ONE masked vector load (lane l reads entry p0+l), broadcast per edge via
// v_readlane. All row loads are then independent -> deep MLP instead of a
// serial list->oth->row chain per edge.
// Lane layout: half = lane>>5 processes edge (t+half); li = lane&31 owns dims
// [4li,4li+4) as float4 (16 B/lane; one load instruction covers 2 rows).
__global__ __launch_bounds__(256) void k_gather(
    const float* __restrict__ node, const float* __restrict__ edge,
    const int* __restrict__ ptr_o, const int* __restrict__ ptr_i,
    const int2* __restrict__ list_o, const int2* __restrict__ list_i,
    float* __restrict__ acc_o, float* __restrict__ acc_i)
{
    int gid = blockIdx.x * 4 + (threadIdx.x >> 6);   // [0, 2*NN)
    int l = threadIdx.x & 63;
    int half = l >> 5;
    int li = l & 31;
    int dirI = gid >= NN;
    int n = gid - (dirI ? NN : 0);
    const int* ptr   = dirI ? ptr_i  : ptr_o;
    const int2* list = dirI ? list_i : list_o;
    float* acc       = dirI ? acc_i  : acc_o;

    int p0 = ptr[n], p1 = ptr[n + 1];
    int deg = p1 - p0;
    int degc = (deg < 64) ? deg : 64;

    int2 eu = make_int2(0, 0);
    if (l < degc) eu = list[p0 + l];

    float4_t a = {0.f, 0.f, 0.f, 0.f};
    for (int t = 0; t < degc; t += 2) {
        int tb = (t + 1 < degc) ? (t + 1) : t;
        int e0 = __builtin_amdgcn_readlane(eu.x, t);
        int u0 = __builtin_amdgcn_readlane(eu.y, t);
        int e1 = __builtin_amdgcn_readlane(eu.x, tb);
        int u1 = __builtin_amdgcn_readlane(eu.y, tb);
        int e = half ? e1 : e0;
        int u = half ? u1 : u0;
        if (t + half < degc) {
            float4_t x = *((const float4_t*)(node + (size_t)u * DD) + li);
            float4_t y = *((const float4_t*)(edge + (size_t)e * DD) + li);
            a += x - y;
        }
    }
    // rare deg > 64 tail: direct walk, two edges in flight (one per half)
    for (int j = p0 + 64 + half; j < p1; j += 2) {
        int2 t = list[j];
        float4_t x = *((const float4_t*)(node + (size_t)t.y * DD) + li);
        float4_t y = *((const float4_t*)(edge + (size_t)t.x * DD) + li);
        a += x - y;
    }

    // combine the two halves (even-edge partial + odd-edge partial)
    float4_t b;
    #pragma unroll
    for (int c = 0; c < 4; c++) b[c] = __shfl_xor(a[c], 32);
    a += b;

    float inv = (deg > 0) ? 1.0f / (float)deg : 0.0f;
    a *= inv;
    if (half == 0)
        *((float4_t*)(acc + (size_t)n * DD) + li) = a;
}

// ---------- MFMA GEMM: 32 rows x 128 cols per block, K=384 (3 x 128 concat) ----------
// Wave w: cols [32w, 32w+32), 2x2 tiles of 16x16 via mfma_f32_16x16x32_bf16.
// Inputs staged f32 -> bf16 into LDS (stride 40 shorts = 80 B: 16B-aligned frags,
// <=2-way bank aliasing). Writes h (f32, overlays acc_o rows of this block only)
// plus per-column BN partials.
__global__ __launch_bounds__(256) void k_gemm(
    const float* acc_o, const float* acc_i,
    const float* __restrict__ node,
    const float* __restrict__ W0, const float* __restrict__ W1, const float* __restrict__ W2,
    const float* __restrict__ b0, const float* __restrict__ b1, const float* __restrict__ b2,
    float* h, float* __restrict__ col_sum, float* __restrict__ col_sumsq)
{
    __shared__ unsigned short s_a[32 * 40];    // 2560 B
    __shared__ unsigned short s_b[128 * 40];   // 10240 B
    __shared__ float s_red[2 * 4 * 128];       // 4096 B

    const int tid = threadIdx.x;
    const int n0 = blockIdx.x * 32;
    const int w  = tid >> 6;
    const int l  = tid & 63;
    const int q  = l >> 4;
    const int li = l & 15;

    float4_t acc[2][2];
    #pragma unroll
    for (int i = 0; i < 2; i++)
        #pragma unroll
        for (int j = 0; j < 2; j++) acc[i][j] = (float4_t){0.f, 0.f, 0.f, 0.f};

    const int srow = tid >> 3;      // 0..31
    const int skq  = tid & 7;       // float4 slot 0..7

    for (int kc = 0; kc < 12; kc++) {
        const int m  = kc >> 2;
        const int k0 = (kc & 3) * 32;
        const float* X = (m == 0) ? acc_o : (m == 1) ? acc_i : node;
        const float* W = (m == 0) ? W0    : (m == 1) ? W1    : W2;

        __syncthreads();   // frag reads of previous chunk complete

        // stage A: 32 rows x 32 k
        {
            float4 v = *(const float4*)&X[(size_t)(n0 + srow) * DD + k0 + 4 * skq];
            ushort4 o = { f2bf(v.x), f2bf(v.y), f2bf(v.z), f2bf(v.w) };
            *(ushort4*)&s_a[srow * 40 + 4 * skq] = o;
        }
        // stage B: 128 c-rows x 32 k
        #pragma unroll
        for (int p = 0; p < 4; p++) {
            int row = 32 * p + srow;
            float4 v = *(const float4*)&W[row * DD + k0 + 4 * skq];
            ushort4 o = { f2bf(v.x), f2bf(v.y), f2bf(v.z), f2bf(v.w) };
            *(ushort4*)&s_b[row * 40 + 4 * skq] = o;
        }
        __syncthreads();

        short8_t af0 = *(const short8_t*)&s_a[li * 40 + q * 8];
        short8_t af1 = *(const short8_t*)&s_a[(16 + li) * 40 + q * 8];
        short8_t bf0 = *(const short8_t*)&s_b[(32 * w + li) * 40 + q * 8];
        short8_t bf1 = *(const short8_t*)&s_b[(32 * w + 16 + li) * 40 + q * 8];

        acc[0][0] = __builtin_amdgcn_mfma_f32_16x16x32_bf16(af0, bf0, acc[0][0], 0, 0, 0);
        acc[0][1] = __builtin_amdgcn_mfma_f32_16x16x32_bf16(af0, bf1, acc[0][1], 0, 0, 0);
        acc[1][0] = __builtin_amdgcn_mfma_f32_16x16x32_bf16(af1, bf0, acc[1][0], 0, 0, 0);
        acc[1][1] = __builtin_amdgcn_mfma_f32_16x16x32_bf16(af1, bf1, acc[1][1], 0, 0, 0);
    }

    // epilogue: bias, /3, store h, BN partials
    // C/D layout: col = lane&15 (within 16-tile), row = (lane>>4)*4 + reg
    const float third = 1.0f / 3.0f;
    #pragma unroll
    for (int j = 0; j < 2; j++) {
        int c = 32 * w + 16 * j + li;
        float bsum = b0[c] + b1[c] + b2[c];
        float s = 0.f, sq = 0.f;
        #pragma unroll
        for (int i = 0; i < 2; i++)
            #pragma unroll
            for (int reg = 0; reg < 4; reg++) {
                int r = n0 + 16 * i + q * 4 + reg;
                float v = (acc[i][j][reg] + bsum) * third;
                h[(size_t)r * DD + c] = v;
                s += v; sq += v * v;
            }
        s_red[q * 128 + c]       = s;
        s_red[512 + q * 128 + c] = sq;
    }
    __syncthreads();
    if (tid < 128) {
        float s = 0.f, sq = 0.f;
        #pragma unroll
        for (int r4 = 0; r4 < 4; r4++) {
            s  += s_red[r4 * 128 + tid];
            sq += s_red[512 + r4 * 128 + tid];
        }
        unsafeAtomicAdd(col_sum + tid, s);
        unsafeAtomicAdd(col_sumsq + tid, sq);
    }
}

__global__ void k_stats(const float* __restrict__ col_sum, const float* __restrict__ col_sumsq,
                        const float* __restrict__ gamma, const float* __restrict__ beta,
                        float* __restrict__ sc, float* __restrict__ bs)
{
    int t = threadIdx.x;
    float mu  = col_sum[t]   * (1.0f / NN);
    float var = col_sumsq[t] * (1.0f / NN) - mu * mu;
    var = fmaxf(var, 0.0f);
    float rs = rsqrtf(var + 1e-5f);
    float g = gamma[t];
    sc[t] = rs * g;
    bs[t] = beta[t] - mu * rs * g;
}

__global__ __launch_bounds__(256) void k_norm(const float* __restrict__ h,
        const float* __restrict__ sc, const float* __restrict__ bs,
        float* __restrict__ out)
{
    __shared__ float ssc[128], sbs[128];
    int tid = threadIdx.x;
    if (tid < 128) { ssc[tid] = sc[tid]; sbs[tid] = bs[tid]; }
    __syncthreads();
    size_t base = ((size_t)blockIdx.x * 256 + tid) * 4;
    float4 v = *(const float4*)(h + base);
    int j = (int)(base & 127);
    float4 o;
    o.x = fmaf(v.x, ssc[j],     sbs[j]);
    o.y = fmaf(v.y, ssc[j + 1], sbs[j + 1]);
    o.z = fmaf(v.z, ssc[j + 2], sbs[j + 2]);
    o.w = fmaf(v.w, ssc[j + 3], sbs[j + 3]);
    *(float4*)(out + base) = o;
}

extern "C" void kernel_launch(void* const* d_in, const int* in_sizes, int n_in,
                              void* d_out, int out_size, void* d_ws, size_t ws_size,
                              hipStream_t stream)
{
    const float* node  = (const float*)d_in[0];
    const float* edge  = (const float*)d_in[1];
    const float* W0    = (const float*)d_in[2];
    const float* b0    = (const float*)d_in[3];
    const float* W1    = (const float*)d_in[4];
    const float* b1    = (const float*)d_in[5];
    const float* W2    = (const float*)d_in[6];
    const float* b2    = (const float*)d_in[7];
    const float* gamma = (const float*)d_in[8];
    const float* beta  = (const float*)d_in[9];
    const int* src = (const int*)d_in[10];
    const int* dst = (const int*)d_in[11];
    float* out = (float*)d_out;

    const size_t NB = (size_t)NN * DD;
    float* acc_o = (float*)d_ws;           // NB floats
    float* acc_i = acc_o + NB;             // NB floats
    // ---- zeroed region ----
    int* cnt_o = (int*)(acc_i + NB);       // NN
    int* cnt_i = cnt_o + NN;               // NN
    int* cur_o = cnt_i + NN;               // NN
    int* cur_i = cur_o + NN;               // NN
    float* col_sum   = (float*)(cur_i + NN);   // 128
    float* col_sumsq = col_sum + DD;           // 128
    // ---- end zeroed region ----
    int* ptr_o = (int*)(col_sumsq + DD);   // NN+1
    int* ptr_i = ptr_o + (NN + 1);         // NN+1
    int* bsum  = ptr_i + (NN + 1);         // 2*128
    int2* list_o = (int2*)(bsum + 256);    // NE int2
    int2* list_i = list_o + NE;            // NE int2
    float* sc = (float*)(list_i + NE);     // 128
    float* bs = sc + DD;                   // 128
    float* h  = acc_o;                     // reuse acc_o for h (per-block in-place safe)

    size_t zbytes = (size_t)(4 * NN + 2 * DD) * sizeof(int);
    hipMemsetAsync(cnt_o, 0, zbytes, stream);

    int egrid = (NE + 255) / 256;
    k_hist <<<egrid, 256, 0, stream>>>(src, dst, cnt_o, cnt_i);
    k_scanA<<<dim3(NBLK, 2), 256, 0, stream>>>(cnt_o, cnt_i, ptr_o, ptr_i, bsum);
    k_scanB<<<dim3(1, 2), 128, 0, stream>>>(bsum);
    k_scanC<<<dim3(NBLK, 2), 256, 0, stream>>>(ptr_o, ptr_i, bsum);
    k_fill <<<egrid, 256, 0, stream>>>(src, dst, ptr_o, ptr_i, cur_o, cur_i, list_o, list_i);
    k_gather<<<(2 * NN) / 4, 256, 0, stream>>>(node, edge,
                                               ptr_o, ptr_i, list_o, list_i, acc_o, acc_i);
    k_gemm<<<NN / 32, 256, 0, stream>>>(acc_o, acc_i, node,
                                        W0, W1, W2, b0, b1, b2,
                                        h, col_sum, col_sumsq);
    k_stats<<<1, 128, 0, stream>>>(col_sum, col_sumsq, gamma, beta, sc, bs);
    k_norm<<<(NN * DD) / 1024, 256, 0, stream>>>(h, sc, bs, out);
}

// Round 2
// 827.099 us; speedup vs baseline: 1.1205x; 1.0003x over previous
//
#include <hip/hip_runtime.h>
#include <hip/hip_bf16.h>

#define NN 100000
#define NE 600000
#define DD 128
#define NBLK 98   // ceil(NN/1024)

typedef __attribute__((ext_vector_type(8))) short short8_t;
typedef __attribute__((ext_vector_type(4))) float float4_t;

__device__ __forceinline__ unsigned short f2bf(float f) {
    union { float f; unsigned int i; } v; v.f = f;
    unsigned int r = v.i + 0x7fffu + ((v.i >> 16) & 1u);
    return (unsigned short)(r >> 16);
}

// ---------- counting-sort infrastructure ----------

__global__ __launch_bounds__(256) void k_hist(
    const int* __restrict__ src, const int* __restrict__ dst,
    int* __restrict__ cnt_o, int* __restrict__ cnt_i)
{
    int e = blockIdx.x * 256 + threadIdx.x;
    if (e < NE) {
        atomicAdd(&cnt_o[dst[e]], 1);
        atomicAdd(&cnt_i[src[e]], 1);
    }
}

__global__ __launch_bounds__(256) void k_scanA(
    const int* __restrict__ cnt_o, const int* __restrict__ cnt_i,
    int* __restrict__ ptr_o, int* __restrict__ ptr_i, int* __restrict__ bsum)
{
    __shared__ int sh[256];
    const int* cnt = blockIdx.y ? cnt_i : cnt_o;
    int* ptr       = blockIdx.y ? ptr_i : ptr_o;
    int t = threadIdx.x;
    int base = blockIdx.x * 1024 + t * 4;
    int c[4];
    #pragma unroll
    for (int j = 0; j < 4; j++) c[j] = (base + j < NN) ? cnt[base + j] : 0;
    int s = c[0] + c[1] + c[2] + c[3];
    sh[t] = s;
    __syncthreads();
    for (int off = 1; off < 256; off <<= 1) {
        int v = (t >= off) ? sh[t - off] : 0;
        __syncthreads();
        sh[t] += v;
        __syncthreads();
    }
    int excl = sh[t] - s;
    int e0 = excl, e1 = e0 + c[0], e2 = e1 + c[1], e3 = e2 + c[2];
    if (base     < NN) ptr[base]     = e0;
    if (base + 1 < NN) ptr[base + 1] = e1;
    if (base + 2 < NN) ptr[base + 2] = e2;
    if (base + 3 < NN) ptr[base + 3] = e3;
    if (t == 255) bsum[blockIdx.y * 128 + blockIdx.x] = sh[255];
}

__global__ __launch_bounds__(128) void k_scanB(int* __restrict__ bsum)
{
    __shared__ int sh[128];
    int t = threadIdx.x;
    int* b = bsum + blockIdx.y * 128;
    int v = (t < NBLK) ? b[t] : 0;
    sh[t] = v;
    __syncthreads();
    for (int off = 1; off < 128; off <<= 1) {
        int u = (t >= off) ? sh[t - off] : 0;
        __syncthreads();
        sh[t] += u;
        __syncthreads();
    }
    b[t] = sh[t] - v;   // exclusive
}

__global__ __launch_bounds__(256) void k_scanC(
    int* __restrict__ ptr_o, int* __restrict__ ptr_i, const int* __restrict__ bsum)
{
    int* ptr = blockIdx.y ? ptr_i : ptr_o;
    int off = bsum[blockIdx.y * 128 + blockIdx.x];
    int base = blockIdx.x * 1024 + threadIdx.x * 4;
    #pragma unroll
    for (int j = 0; j < 4; j++)
        if (base + j < NN) ptr[base + j] += off;
    if (blockIdx.x == 0 && threadIdx.x == 0) ptr[NN] = NE;
}

// Adjacency entries carry (edge_id, other_endpoint) so k_gather has no
// dependent index chase: list -> row loads directly.
__global__ __launch_bounds__(256) void k_fill(
    const int* __restrict__ src, const int* __restrict__ dst,
    const int* __restrict__ ptr_o, const int* __restrict__ ptr_i,
    int* __restrict__ cur_o, int* __restrict__ cur_i,
    int2* __restrict__ list_o, int2* __restrict__ list_i)
{
    int e = blockIdx.x * 256 + threadIdx.x;
    if (e < NE) {
        int s = src[e], t = dst[e];
        int p = atomicAdd(&cur_o[t], 1);
        list_o[ptr_o[t] + p] = make_int2(e, s);
        int q = atomicAdd(&cur_i[s], 1);
        list_i[ptr_i[s] + q] = make_int2(e, t);
    }
}

// ---------- gather: one wave per (node, direction) ----------
// Latency-optimized v2: adjacency (e,u) prefetched in one masked vector load;
// main loop batches 8 edges (4 per 32-lane half), issuing all 8 row-load
// instructions UNCONDITIONALLY (out-of-range lanes hold (0,0) -> valid row-0
// address) before any accumulate. Accumulation is mask-multiply FMA, so there
// is no exec-mask churn and the compiler can keep all 8 loads in flight.
// Lane layout: half = lane>>5 processes odd/even edges; li = lane&31 owns dims
// [4li, 4li+4) as float4 (16 B/lane; one load instruction covers 2 rows).
__global__ __launch_bounds__(256) void k_gather(
    const float* __restrict__ node, const float* __restrict__ edge,
    const int* __restrict__ ptr_o, const int* __restrict__ ptr_i,
    const int2* __restrict__ list_o, const int2* __restrict__ list_i,
    float* __restrict__ acc_o, float* __restrict__ acc_i)
{
    int gid = blockIdx.x * 4 + (threadIdx.x >> 6);   // [0, 2*NN)
    int l = threadIdx.x & 63;
    int half = l >> 5;
    int li = l & 31;
    int dirI = gid >= NN;
    int n = gid - (dirI ? NN : 0);
    const int* ptr   = dirI ? ptr_i  : ptr_o;
    const int2* list = dirI ? list_i : list_o;
    float* acc       = dirI ? acc_i  : acc_o;

    int p0 = ptr[n], p1 = ptr[n + 1];
    int deg = p1 - p0;
    int degc = (deg < 64) ? deg : 64;

    int2 eu = make_int2(0, 0);
    if (l < degc) eu = list[p0 + l];

    float4_t a = {0.f, 0.f, 0.f, 0.f};
    for (int t = 0; t < degc; t += 8) {
        int es[4], us[4];
        float ms[4];
        float4_t xs[4], ys[4];
        #pragma unroll
        for (int b = 0; b < 4; b++) {
            int i0 = t + 2 * b;
            int l0 = (i0     < 64) ? i0     : 0;   // wave-uniform clamp (SALU)
            int l1 = (i0 + 1 < 64) ? i0 + 1 : 0;
            int e0 = __builtin_amdgcn_readlane(eu.x, l0);
            int u0 = __builtin_amdgcn_readlane(eu.y, l0);
            int e1 = __builtin_amdgcn_readlane(eu.x, l1);
            int u1 = __builtin_amdgcn_readlane(eu.y, l1);
            es[b] = half ? e1 : e0;
            us[b] = half ? u1 : u0;
            ms[b] = (i0 + half < degc) ? 1.0f : 0.0f;
        }
        #pragma unroll
        for (int b = 0; b < 4; b++) {
            xs[b] = *((const float4_t*)(node + (size_t)us[b] * DD) + li);
            ys[b] = *((const float4_t*)(edge + (size_t)es[b] * DD) + li);
        }
        #pragma unroll
        for (int b = 0; b < 4; b++) {
            #pragma unroll
            for (int c = 0; c < 4; c++)
                a[c] = fmaf(xs[b][c] - ys[b][c], ms[b], a[c]);
        }
    }
    // rare deg > 64 tail: direct walk, two edges in flight (one per half)
    for (int j = p0 + 64 + half; j < p1; j += 2) {
        int2 t = list[j];
        float4_t x = *((const float4_t*)(node + (size_t)t.y * DD) + li);
        float4_t y = *((const float4_t*)(edge + (size_t)t.x * DD) + li);
        a += x - y;
    }

    // combine the two halves (even-edge partial + odd-edge partial)
    float4_t b;
    #pragma unroll
    for (int c = 0; c < 4; c++) b[c] = __shfl_xor(a[c], 32);
    a += b;

    float inv = (deg > 0) ? 1.0f / (float)deg : 0.0f;
    a *= inv;
    if (half == 0)
        *((float4_t*)(acc + (size_t)n * DD) + li) = a;
}

// ---------- MFMA GEMM: 32 rows x 128 cols per block, K=384 (3 x 128 concat) ----------
// Wave w: cols [32w, 32w+32), 2x2 tiles of 16x16 via mfma_f32_16x16x32_bf16.
// Inputs staged f32 -> bf16 into LDS (stride 40 shorts = 80 B: 16B-aligned frags,
// <=2-way bank aliasing). Writes h (f32, overlays acc_o rows of this block only)
// plus per-column BN partials.
__global__ __launch_bounds__(256) void k_gemm(
    const float* acc_o, const float* acc_i,
    const float* __restrict__ node,
    const float* __restrict__ W0, const float* __restrict__ W1, const float* __restrict__ W2,
    const float* __restrict__ b0, const float* __restrict__ b1, const float* __restrict__ b2,
    float* h, float* __restrict__ col_sum, float* __restrict__ col_sumsq)
{
    __shared__ unsigned short s_a[32 * 40];    // 2560 B
    __shared__ unsigned short s_b[128 * 40];   // 10240 B
    __shared__ float s_red[2 * 4 * 128];       // 4096 B

    const int tid = threadIdx.x;
    const int n0 = blockIdx.x * 32;
    const int w  = tid >> 6;
    const int l  = tid & 63;
    const int q  = l >> 4;
    const int li = l & 15;

    float4_t acc[2][2];
    #pragma unroll
    for (int i = 0; i < 2; i++)
        #pragma unroll
        for (int j = 0; j < 2; j++) acc[i][j] = (float4_t){0.f, 0.f, 0.f, 0.f};

    const int srow = tid >> 3;      // 0..31
    const int skq  = tid & 7;       // float4 slot 0..7

    for (int kc = 0; kc < 12; kc++) {
        const int m  = kc >> 2;
        const int k0 = (kc & 3) * 32;
        const float* X = (m == 0) ? acc_o : (m == 1) ? acc_i : node;
        const float* W = (m == 0) ? W0    : (m == 1) ? W1    : W2;

        __syncthreads();   // frag reads of previous chunk complete

        // stage A: 32 rows x 32 k
        {
            float4 v = *(const float4*)&X[(size_t)(n0 + srow) * DD + k0 + 4 * skq];
            ushort4 o = { f2bf(v.x), f2bf(v.y), f2bf(v.z), f2bf(v.w) };
            *(ushort4*)&s_a[srow * 40 + 4 * skq] = o;
        }
        // stage B: 128 c-rows x 32 k
        #pragma unroll
        for (int p = 0; p < 4; p++) {
            int row = 32 * p + srow;
            float4 v = *(const float4*)&W[row * DD + k0 + 4 * skq];
            ushort4 o = { f2bf(v.x), f2bf(v.y), f2bf(v.z), f2bf(v.w) };
            *(ushort4*)&s_b[row * 40 + 4 * skq] = o;
        }
        __syncthreads();

        short8_t af0 = *(const short8_t*)&s_a[li * 40 + q * 8];
        short8_t af1 = *(const short8_t*)&s_a[(16 + li) * 40 + q * 8];
        short8_t bf0 = *(const short8_t*)&s_b[(32 * w + li) * 40 + q * 8];
        short8_t bf1 = *(const short8_t*)&s_b[(32 * w + 16 + li) * 40 + q * 8];

        acc[0][0] = __builtin_amdgcn_mfma_f32_16x16x32_bf16(af0, bf0, acc[0][0], 0, 0, 0);
        acc[0][1] = __builtin_amdgcn_mfma_f32_16x16x32_bf16(af0, bf1, acc[0][1], 0, 0, 0);
        acc[1][0] = __builtin_amdgcn_mfma_f32_16x16x32_bf16(af1, bf0, acc[1][0], 0, 0, 0);
        acc[1][1] = __builtin_amdgcn_mfma_f32_16x16x32_bf16(af1, bf1, acc[1][1], 0, 0, 0);
    }

    // epilogue: bias, /3, store h, BN partials
    // C/D layout: col = lane&15 (within 16-tile), row = (lane>>4)*4 + reg
    const float third = 1.0f / 3.0f;
    #pragma unroll
    for (int j = 0; j < 2; j++) {
        int c = 32 * w + 16 * j + li;
        float bsum = b0[c] + b1[c] + b2[c];
        float s = 0.f, sq = 0.f;
        #pragma unroll
        for (int i = 0; i < 2; i++)
            #pragma unroll
            for (int reg = 0; reg < 4; reg++) {
                int r = n0 + 16 * i + q * 4 + reg;
                float v = (acc[i][j][reg] + bsum) * third;
                h[(size_t)r * DD + c] = v;
                s += v; sq += v * v;
            }
        s_red[q * 128 + c]       = s;
        s_red[512 + q * 128 + c] = sq;
    }
    __syncthreads();
    if (tid < 128) {
        float s = 0.f, sq = 0.f;
        #pragma unroll
        for (int r4 = 0; r4 < 4; r4++) {
            s  += s_red[r4 * 128 + tid];
            sq += s_red[512 + r4 * 128 + tid];
        }
        unsafeAtomicAdd(col_sum + tid, s);
        unsafeAtomicAdd(col_sumsq + tid, sq);
    }
}

__global__ void k_stats(const float* __restrict__ col_sum, const float* __restrict__ col_sumsq,
                        const float* __restrict__ gamma, const float* __restrict__ beta,
                        float* __restrict__ sc, float* __restrict__ bs)
{
    int t = threadIdx.x;
    float mu  = col_sum[t]   * (1.0f / NN);
    float var = col_sumsq[t] * (1.0f / NN) - mu * mu;
    var = fmaxf(var, 0.0f);
    float rs = rsqrtf(var + 1e-5f);
    float g = gamma[t];
    sc[t] = rs * g;
    bs[t] = beta[t] - mu * rs * g;
}

__global__ __launch_bounds__(256) void k_norm(const float* __restrict__ h,
        const float* __restrict__ sc, const float* __restrict__ bs,
        float* __restrict__ out)
{
    __shared__ float ssc[128], sbs[128];
    int tid = threadIdx.x;
    if (tid < 128) { ssc[tid] = sc[tid]; sbs[tid] = bs[tid]; }
    __syncthreads();
    size_t base = ((size_t)blockIdx.x * 256 + tid) * 4;
    float4 v = *(const float4*)(h + base);
    int j = (int)(base & 127);
    float4 o;
    o.x = fmaf(v.x, ssc[j],     sbs[j]);
    o.y = fmaf(v.y, ssc[j + 1], sbs[j + 1]);
    o.z = fmaf(v.z, ssc[j + 2], sbs[j + 2]);
    o.w = fmaf(v.w, ssc[j + 3], sbs[j + 3]);
    *(float4*)(out + base) = o;
}

extern "C" void kernel_launch(void* const* d_in, const int* in_sizes, int n_in,
                              void* d_out, int out_size, void* d_ws, size_t ws_size,
                              hipStream_t stream)
{
    const float* node  = (const float*)d_in[0];
    const float* edge  = (const float*)d_in[1];
    const float* W0    = (const float*)d_in[2];
    const float* b0    = (const float*)d_in[3];
    const float* W1    = (const float*)d_in[4];
    const float* b1    = (const float*)d_in[5];
    const float* W2    = (const float*)d_in[6];
    const float* b2    = (const float*)d_in[7];
    const float* gamma = (const float*)d_in[8];
    const float* beta  = (const float*)d_in[9];
    const int* src = (const int*)d_in[10];
    const int* dst = (const int*)d_in[11];
    float* out = (float*)d_out;

    const size_t NB = (size_t)NN * DD;
    float* acc_o = (float*)d_ws;           // NB floats
    float* acc_i = acc_o + NB;             // NB floats
    // ---- zeroed region ----
    int* cnt_o = (int*)(acc_i + NB);       // NN
    int* cnt_i = cnt_o + NN;               // NN
    int* cur_o = cnt_i + NN;               // NN
    int* cur_i = cur_o + NN;               // NN
    float* col_sum   = (float*)(cur_i + NN);   // 128
    float* col_sumsq = col_sum + DD;           // 128
    // ---- end zeroed region ----
    int* ptr_o = (int*)(col_sumsq + DD);   // NN+1
    int* ptr_i = ptr_o + (NN + 1);         // NN+1
    int* bsum  = ptr_i + (NN + 1);         // 2*128
    int2* list_o = (int2*)(bsum + 256);    // NE int2
    int2* list_i = list_o + NE;            // NE int2
    float* sc = (float*)(list_i + NE);     // 128
    float* bs = sc + DD;                   // 128
    float* h  = acc_o;                     // reuse acc_o for h (per-block in-place safe)

    size_t zbytes = (size_t)(4 * NN + 2 * DD) * sizeof(int);
    hipMemsetAsync(cnt_o, 0, zbytes, stream);

    int egrid = (NE + 255) / 256;
    k_hist <<<egrid, 256, 0, stream>>>(src, dst, cnt_o, cnt_i);
    k_scanA<<<dim3(NBLK, 2), 256, 0, stream>>>(cnt_o, cnt_i, ptr_o, ptr_i, bsum);
    k_scanB<<<dim3(1, 2), 128, 0, stream>>>(bsum);
    k_scanC<<<dim3(NBLK, 2), 256, 0, stream>>>(ptr_o, ptr_i, bsum);
    k_fill <<<egrid, 256, 0, stream>>>(src, dst, ptr_o, ptr_i, cur_o, cur_i, list_o, list_i);
    k_gather<<<(2 * NN) / 4, 256, 0, stream>>>(node, edge,
                                               ptr_o, ptr_i, list_o, list_i, acc_o, acc_i);
    k_gemm<<<NN / 32, 256, 0, stream>>>(acc_o, acc_i, node,
                                        W0, W1, W2, b0, b1, b2,
                                        h, col_sum, col_sumsq);
    k_stats<<<1, 128, 0, stream>>>(col_sum, col_sumsq, gamma, beta, sc, bs);
    k_norm<<<(NN * DD) / 1024, 256, 0, stream>>>(h, sc, bs, out);
}

// Round 3
// 759.179 us; speedup vs baseline: 1.2208x; 1.0895x over previous
//
#include <hip/hip_runtime.h>
#include <hip/hip_bf16.h>

#define NN 100000
#define NE 600000
#define DD 128
#define NBLK 98   // ceil(NN/1024)

typedef __attribute__((ext_vector_type(8))) short short8_t;
typedef __attribute__((ext_vector_type(4))) float float4_t;

__device__ __forceinline__ unsigned short f2bf(float f) {
    union { float f; unsigned int i; } v; v.f = f;
    unsigned int r = v.i + 0x7fffu + ((v.i >> 16) & 1u);
    return (unsigned short)(r >> 16);
}

// ---------- counting-sort infrastructure ----------

__global__ __launch_bounds__(256) void k_hist(
    const int* __restrict__ src, const int* __restrict__ dst,
    int* __restrict__ cnt_o, int* __restrict__ cnt_i)
{
    int e = blockIdx.x * 256 + threadIdx.x;
    if (e < NE) {
        atomicAdd(&cnt_o[dst[e]], 1);
        atomicAdd(&cnt_i[src[e]], 1);
    }
}

__global__ __launch_bounds__(256) void k_scanA(
    const int* __restrict__ cnt_o, const int* __restrict__ cnt_i,
    int* __restrict__ ptr_o, int* __restrict__ ptr_i, int* __restrict__ bsum)
{
    __shared__ int sh[256];
    const int* cnt = blockIdx.y ? cnt_i : cnt_o;
    int* ptr       = blockIdx.y ? ptr_i : ptr_o;
    int t = threadIdx.x;
    int base = blockIdx.x * 1024 + t * 4;
    int c[4];
    #pragma unroll
    for (int j = 0; j < 4; j++) c[j] = (base + j < NN) ? cnt[base + j] : 0;
    int s = c[0] + c[1] + c[2] + c[3];
    sh[t] = s;
    __syncthreads();
    for (int off = 1; off < 256; off <<= 1) {
        int v = (t >= off) ? sh[t - off] : 0;
        __syncthreads();
        sh[t] += v;
        __syncthreads();
    }
    int excl = sh[t] - s;
    int e0 = excl, e1 = e0 + c[0], e2 = e1 + c[1], e3 = e2 + c[2];
    if (base     < NN) ptr[base]     = e0;
    if (base + 1 < NN) ptr[base + 1] = e1;
    if (base + 2 < NN) ptr[base + 2] = e2;
    if (base + 3 < NN) ptr[base + 3] = e3;
    if (t == 255) bsum[blockIdx.y * 128 + blockIdx.x] = sh[255];
}

__global__ __launch_bounds__(128) void k_scanB(int* __restrict__ bsum)
{
    __shared__ int sh[128];
    int t = threadIdx.x;
    int* b = bsum + blockIdx.y * 128;
    int v = (t < NBLK) ? b[t] : 0;
    sh[t] = v;
    __syncthreads();
    for (int off = 1; off < 128; off <<= 1) {
        int u = (t >= off) ? sh[t - off] : 0;
        __syncthreads();
        sh[t] += u;
        __syncthreads();
    }
    b[t] = sh[t] - v;   // exclusive
}

__global__ __launch_bounds__(256) void k_scanC(
    int* __restrict__ ptr_o, int* __restrict__ ptr_i, const int* __restrict__ bsum)
{
    int* ptr = blockIdx.y ? ptr_i : ptr_o;
    int off = bsum[blockIdx.y * 128 + blockIdx.x];
    int base = blockIdx.x * 1024 + threadIdx.x * 4;
    #pragma unroll
    for (int j = 0; j < 4; j++)
        if (base + j < NN) ptr[base + j] += off;
    if (blockIdx.x == 0 && threadIdx.x == 0) ptr[NN] = NE;
}

// Adjacency entries carry (edge_id, other_endpoint) so gather has no
// dependent index chase: list -> row loads directly.
__global__ __launch_bounds__(256) void k_fill(
    const int* __restrict__ src, const int* __restrict__ dst,
    const int* __restrict__ ptr_o, const int* __restrict__ ptr_i,
    int* __restrict__ cur_o, int* __restrict__ cur_i,
    int2* __restrict__ list_o, int2* __restrict__ list_i)
{
    int e = blockIdx.x * 256 + threadIdx.x;
    if (e < NE) {
        int s = src[e], t = dst[e];
        int p = atomicAdd(&cur_o[t], 1);
        list_o[ptr_o[t] + p] = make_int2(e, s);
        int q = atomicAdd(&cur_i[s], 1);
        list_i[ptr_i[s] + q] = make_int2(e, t);
    }
}

// ---------- fused gather + MFMA GEMM ----------
// Block = 32 nodes. Phase 1: stage node rows (A cols 256..383) + W chunk 0;
// 4 waves x 16 (node,dir) gather tasks, results written DIRECTLY to the LDS
// A-tile as bf16 (cols 0..255). No global acc round-trip.
// Phase 2: K-loop over 12 chunks of 32; A from LDS (resident), W chunk
// register-prefetched one iteration ahead, single-buffered s_b.
// A-tile stride 392 shorts (=49x16B): rows 16B-aligned for ds_read_b128.
// s_red overlays s_b (dead by epilogue).
__global__ __launch_bounds__(256) void k_gg(
    const float* __restrict__ node, const float* __restrict__ edge,
    const int* __restrict__ ptr_o, const int* __restrict__ ptr_i,
    const int2* __restrict__ list_o, const int2* __restrict__ list_i,
    const float* __restrict__ W0, const float* __restrict__ W1, const float* __restrict__ W2,
    const float* __restrict__ b0, const float* __restrict__ b1, const float* __restrict__ b2,
    float* __restrict__ h, float* __restrict__ col_sum, float* __restrict__ col_sumsq)
{
    __shared__ unsigned short s_x[32 * 392];   // 25088 B: A tile (K=384 bf16)
    __shared__ unsigned short s_b[128 * 40];   // 10240 B: W chunk; reused as s_red
    float* s_red = (float*)s_b;                // needs 4096 B <= 10240 B

    const int tid = threadIdx.x;
    const int n0 = blockIdx.x * 32;
    const int w  = tid >> 6;
    const int l  = tid & 63;
    const int half = l >> 5;
    const int li32 = l & 31;
    const int q  = l >> 4;
    const int li = l & 15;
    const int srow = tid >> 3;      // 0..31
    const int skq  = tid & 7;       // float4 slot 0..7

    // ---- stage node rows into A cols 256..383 ----
    #pragma unroll
    for (int c4 = 0; c4 < 4; c4++) {
        float4 v = *(const float4*)&node[(size_t)(n0 + srow) * DD + c4 * 32 + 4 * skq];
        ushort4 o = { f2bf(v.x), f2bf(v.y), f2bf(v.z), f2bf(v.w) };
        *(ushort4*)&s_x[srow * 392 + 256 + c4 * 32 + 4 * skq] = o;
    }
    // ---- stage W chunk 0 ----
    #pragma unroll
    for (int p = 0; p < 4; p++) {
        float4 v = *(const float4*)&W0[(32 * p + srow) * DD + 4 * skq];
        ushort4 o = { f2bf(v.x), f2bf(v.y), f2bf(v.z), f2bf(v.w) };
        *(ushort4*)&s_b[(32 * p + srow) * 40 + 4 * skq] = o;
    }

    // ---- gather: 16 (node,dir) tasks per wave, results -> s_x cols 0..255 ----
    for (int it = 0; it < 16; it++) {
        int tsk = w * 16 + it;
        int dirI = tsk >= 32;
        int nl = tsk & 31;
        int n = n0 + nl;
        const int* ptr   = dirI ? ptr_i  : ptr_o;
        const int2* list = dirI ? list_i : list_o;

        int p0 = ptr[n], p1 = ptr[n + 1];
        int deg = p1 - p0;
        int degc = (deg < 64) ? deg : 64;

        int2 eu = make_int2(0, 0);
        if (l < degc) eu = list[p0 + l];

        float4_t a = {0.f, 0.f, 0.f, 0.f};
        for (int t = 0; t < degc; t += 8) {
            int es[4], us[4];
            float ms[4];
            float4_t xs[4], ys[4];
            #pragma unroll
            for (int b = 0; b < 4; b++) {
                int i0 = t + 2 * b;
                int l0 = (i0     < 64) ? i0     : 0;   // wave-uniform clamp
                int l1 = (i0 + 1 < 64) ? i0 + 1 : 0;
                int e0 = __builtin_amdgcn_readlane(eu.x, l0);
                int u0 = __builtin_amdgcn_readlane(eu.y, l0);
                int e1 = __builtin_amdgcn_readlane(eu.x, l1);
                int u1 = __builtin_amdgcn_readlane(eu.y, l1);
                es[b] = half ? e1 : e0;
                us[b] = half ? u1 : u0;
                ms[b] = (i0 + half < degc) ? 1.0f : 0.0f;
            }
            #pragma unroll
            for (int b = 0; b < 4; b++) {
                xs[b] = *((const float4_t*)(node + (size_t)us[b] * DD) + li32);
                ys[b] = *((const float4_t*)(edge + (size_t)es[b] * DD) + li32);
            }
            #pragma unroll
            for (int b = 0; b < 4; b++) {
                #pragma unroll
                for (int c = 0; c < 4; c++)
                    a[c] = fmaf(xs[b][c] - ys[b][c], ms[b], a[c]);
            }
        }
        // rare deg > 64 tail
        for (int j = p0 + 64 + half; j < p1; j += 2) {
            int2 t2 = list[j];
            float4_t x = *((const float4_t*)(node + (size_t)t2.y * DD) + li32);
            float4_t y = *((const float4_t*)(edge + (size_t)t2.x * DD) + li32);
            a += x - y;
        }
        float4_t bsh;
        #pragma unroll
        for (int c = 0; c < 4; c++) bsh[c] = __shfl_xor(a[c], 32);
        a += bsh;
        float inv = (deg > 0) ? 1.0f / (float)deg : 0.0f;
        a *= inv;
        if (half == 0) {
            ushort4 o = { f2bf(a[0]), f2bf(a[1]), f2bf(a[2]), f2bf(a[3]) };
            *(ushort4*)&s_x[nl * 392 + dirI * 128 + 4 * li32] = o;
        }
    }
    __syncthreads();

    // ---- GEMM K-loop: 12 chunks of 32 ----
    float4_t acc[2][2];
    #pragma unroll
    for (int i = 0; i < 2; i++)
        #pragma unroll
        for (int j = 0; j < 2; j++) acc[i][j] = (float4_t){0.f, 0.f, 0.f, 0.f};

    float4 wv[4];
    for (int kc = 0; kc < 12; kc++) {
        if (kc < 11) {   // issue next W chunk loads early (hidden under MFMA)
            int kn = kc + 1;
            const float* W = (kn < 4) ? W0 : (kn < 8) ? W1 : W2;
            int k0 = (kn & 3) * 32;
            #pragma unroll
            for (int p = 0; p < 4; p++)
                wv[p] = *(const float4*)&W[(32 * p + srow) * DD + k0 + 4 * skq];
        }
        short8_t af0 = *(const short8_t*)&s_x[li * 392 + kc * 32 + q * 8];
        short8_t af1 = *(const short8_t*)&s_x[(16 + li) * 392 + kc * 32 + q * 8];
        short8_t bf0 = *(const short8_t*)&s_b[(32 * w + li) * 40 + q * 8];
        short8_t bf1 = *(const short8_t*)&s_b[(32 * w + 16 + li) * 40 + q * 8];

        acc[0][0] = __builtin_amdgcn_mfma_f32_16x16x32_bf16(af0, bf0, acc[0][0], 0, 0, 0);
        acc[0][1] = __builtin_amdgcn_mfma_f32_16x16x32_bf16(af0, bf1, acc[0][1], 0, 0, 0);
        acc[1][0] = __builtin_amdgcn_mfma_f32_16x16x32_bf16(af1, bf0, acc[1][0], 0, 0, 0);
        acc[1][1] = __builtin_amdgcn_mfma_f32_16x16x32_bf16(af1, bf1, acc[1][1], 0, 0, 0);

        if (kc < 11) {
            __syncthreads();   // all waves done reading s_b
            #pragma unroll
            for (int p = 0; p < 4; p++) {
                ushort4 o = { f2bf(wv[p].x), f2bf(wv[p].y), f2bf(wv[p].z), f2bf(wv[p].w) };
                *(ushort4*)&s_b[(32 * p + srow) * 40 + 4 * skq] = o;
            }
            __syncthreads();   // writes visible
        }
    }
    __syncthreads();   // frag reads done before s_red overlays s_b

    // epilogue: bias, /3, store h, BN partials
    // C/D layout: col = lane&15 (within 16-tile), row = (lane>>4)*4 + reg
    const float third = 1.0f / 3.0f;
    #pragma unroll
    for (int j = 0; j < 2; j++) {
        int c = 32 * w + 16 * j + li;
        float bsum = b0[c] + b1[c] + b2[c];
        float s = 0.f, sq = 0.f;
        #pragma unroll
        for (int i = 0; i < 2; i++)
            #pragma unroll
            for (int reg = 0; reg < 4; reg++) {
                int r = n0 + 16 * i + q * 4 + reg;
                float v = (acc[i][j][reg] + bsum) * third;
                h[(size_t)r * DD + c] = v;
                s += v; sq += v * v;
            }
        s_red[q * 128 + c]       = s;
        s_red[512 + q * 128 + c] = sq;
    }
    __syncthreads();
    if (tid < 128) {
        float s = 0.f, sq = 0.f;
        #pragma unroll
        for (int r4 = 0; r4 < 4; r4++) {
            s  += s_red[r4 * 128 + tid];
            sq += s_red[512 + r4 * 128 + tid];
        }
        unsafeAtomicAdd(col_sum + tid, s);
        unsafeAtomicAdd(col_sumsq + tid, sq);
    }
}

__global__ void k_stats(const float* __restrict__ col_sum, const float* __restrict__ col_sumsq,
                        const float* __restrict__ gamma, const float* __restrict__ beta,
                        float* __restrict__ sc, float* __restrict__ bs)
{
    int t = threadIdx.x;
    float mu  = col_sum[t]   * (1.0f / NN);
    float var = col_sumsq[t] * (1.0f / NN) - mu * mu;
    var = fmaxf(var, 0.0f);
    float rs = rsqrtf(var + 1e-5f);
    float g = gamma[t];
    sc[t] = rs * g;
    bs[t] = beta[t] - mu * rs * g;
}

__global__ __launch_bounds__(256) void k_norm(const float* __restrict__ h,
        const float* __restrict__ sc, const float* __restrict__ bs,
        float* __restrict__ out)
{
    __shared__ float ssc[128], sbs[128];
    int tid = threadIdx.x;
    if (tid < 128) { ssc[tid] = sc[tid]; sbs[tid] = bs[tid]; }
    __syncthreads();
    size_t base = ((size_t)blockIdx.x * 256 + tid) * 4;
    float4 v = *(const float4*)(h + base);
    int j = (int)(base & 127);
    float4 o;
    o.x = fmaf(v.x, ssc[j],     sbs[j]);
    o.y = fmaf(v.y, ssc[j + 1], sbs[j + 1]);
    o.z = fmaf(v.z, ssc[j + 2], sbs[j + 2]);
    o.w = fmaf(v.w, ssc[j + 3], sbs[j + 3]);
    *(float4*)(out + base) = o;
}

extern "C" void kernel_launch(void* const* d_in, const int* in_sizes, int n_in,
                              void* d_out, int out_size, void* d_ws, size_t ws_size,
                              hipStream_t stream)
{
    const float* node  = (const float*)d_in[0];
    const float* edge  = (const float*)d_in[1];
    const float* W0    = (const float*)d_in[2];
    const float* b0    = (const float*)d_in[3];
    const float* W1    = (const float*)d_in[4];
    const float* b1    = (const float*)d_in[5];
    const float* W2    = (const float*)d_in[6];
    const float* b2    = (const float*)d_in[7];
    const float* gamma = (const float*)d_in[8];
    const float* beta  = (const float*)d_in[9];
    const int* src = (const int*)d_in[10];
    const int* dst = (const int*)d_in[11];
    float* out = (float*)d_out;

    const size_t NB = (size_t)NN * DD;
    float* h = (float*)d_ws;               // NB floats
    // ---- zeroed region ----
    int* cnt_o = (int*)(h + NB);           // NN
    int* cnt_i = cnt_o + NN;               // NN
    int* cur_o = cnt_i + NN;               // NN
    int* cur_i = cur_o + NN;               // NN
    float* col_sum   = (float*)(cur_i + NN);   // 128
    float* col_sumsq = col_sum + DD;           // 128
    // ---- end zeroed region ----
    int* ptr_o = (int*)(col_sumsq + DD);   // NN+1
    int* ptr_i = ptr_o + (NN + 1);         // NN+1
    int* bsum  = ptr_i + (NN + 1);         // 2*128
    int2* list_o = (int2*)(bsum + 256);    // NE int2
    int2* list_i = list_o + NE;            // NE int2
    float* sc = (float*)(list_i + NE);     // 128
    float* bs = sc + DD;                   // 128

    size_t zbytes = (size_t)(4 * NN + 2 * DD) * sizeof(int);
    hipMemsetAsync(cnt_o, 0, zbytes, stream);

    int egrid = (NE + 255) / 256;
    k_hist <<<egrid, 256, 0, stream>>>(src, dst, cnt_o, cnt_i);
    k_scanA<<<dim3(NBLK, 2), 256, 0, stream>>>(cnt_o, cnt_i, ptr_o, ptr_i, bsum);
    k_scanB<<<dim3(1, 2), 128, 0, stream>>>(bsum);
    k_scanC<<<dim3(NBLK, 2), 256, 0, stream>>>(ptr_o, ptr_i, bsum);
    k_fill <<<egrid, 256, 0, stream>>>(src, dst, ptr_o, ptr_i, cur_o, cur_i, list_o, list_i);
    k_gg  <<<NN / 32, 256, 0, stream>>>(node, edge, ptr_o, ptr_i, list_o, list_i,
                                        W0, W1, W2, b0, b1, b2,
                                        h, col_sum, col_sumsq);
    k_stats<<<1, 128, 0, stream>>>(col_sum, col_sumsq, gamma, beta, sc, bs);
    k_norm<<<(NN * DD) / 1024, 256, 0, stream>>>(h, sc, bs, out);
}

// Round 6
// 698.320 us; speedup vs baseline: 1.3271x; 1.0872x over previous
//
#include <hip/hip_runtime.h>
#include <hip/hip_bf16.h>

#define NN 100000
#define NE 600000
#define DD 128
#define NBLK 98   // ceil(NN/1024)

typedef __attribute__((ext_vector_type(8))) short short8_t;
typedef __attribute__((ext_vector_type(4))) float float4_t;

__device__ __forceinline__ unsigned short f2bf(float f) {
    union { float f; unsigned int i; } v; v.f = f;
    unsigned int r = v.i + 0x7fffu + ((v.i >> 16) & 1u);
    return (unsigned short)(r >> 16);
}

// A-tile byte address with T2 XOR swizzle: row stride 768B (384 bf16),
// col-byte bits 4-6 XORed with row&7 -> each 8-lane cycle-group of a
// ds_read_b128 frag read covers all 32 banks (conflict-free).
#define AX(row, cb) ((row) * 768 + ((cb) ^ (((row) & 7) << 4)))

// ---------- counting-sort infrastructure ----------

// hist also records each edge's rank (atomicAdd return) so k_fill is atomic-free.
__global__ __launch_bounds__(256) void k_hist(
    const int* __restrict__ src, const int* __restrict__ dst,
    int* __restrict__ cnt_o, int* __restrict__ cnt_i,
    int* __restrict__ rank_o, int* __restrict__ rank_i)
{
    int e = blockIdx.x * 256 + threadIdx.x;
    if (e < NE) {
        rank_o[e] = atomicAdd(&cnt_o[dst[e]], 1);
        rank_i[e] = atomicAdd(&cnt_i[src[e]], 1);
    }
}

__global__ __launch_bounds__(256) void k_scanA(
    const int* __restrict__ cnt_o, const int* __restrict__ cnt_i,
    int* __restrict__ ptr_o, int* __restrict__ ptr_i, int* __restrict__ bsum)
{
    __shared__ int sh[256];
    const int* cnt = blockIdx.y ? cnt_i : cnt_o;
    int* ptr       = blockIdx.y ? ptr_i : ptr_o;
    int t = threadIdx.x;
    int base = blockIdx.x * 1024 + t * 4;
    int c[4];
    #pragma unroll
    for (int j = 0; j < 4; j++) c[j] = (base + j < NN) ? cnt[base + j] : 0;
    int s = c[0] + c[1] + c[2] + c[3];
    sh[t] = s;
    __syncthreads();
    for (int off = 1; off < 256; off <<= 1) {
        int v = (t >= off) ? sh[t - off] : 0;
        __syncthreads();
        sh[t] += v;
        __syncthreads();
    }
    int excl = sh[t] - s;
    int e0 = excl, e1 = e0 + c[0], e2 = e1 + c[1], e3 = e2 + c[2];
    if (base     < NN) ptr[base]     = e0;
    if (base + 1 < NN) ptr[base + 1] = e1;
    if (base + 2 < NN) ptr[base + 2] = e2;
    if (base + 3 < NN) ptr[base + 3] = e3;
    if (t == 255) bsum[blockIdx.y * 128 + blockIdx.x] = sh[255];
}

__global__ __launch_bounds__(128) void k_scanB(int* __restrict__ bsum)
{
    __shared__ int sh[128];
    int t = threadIdx.x;
    int* b = bsum + blockIdx.y * 128;
    int v = (t < NBLK) ? b[t] : 0;
    sh[t] = v;
    __syncthreads();
    for (int off = 1; off < 128; off <<= 1) {
        int u = (t >= off) ? sh[t - off] : 0;
        __syncthreads();
        sh[t] += u;
        __syncthreads();
    }
    b[t] = sh[t] - v;   // exclusive
}

__global__ __launch_bounds__(256) void k_scanC(
    int* __restrict__ ptr_o, int* __restrict__ ptr_i, const int* __restrict__ bsum)
{
    int* ptr = blockIdx.y ? ptr_i : ptr_o;
    int off = bsum[blockIdx.y * 128 + blockIdx.x];
    int base = blockIdx.x * 1024 + threadIdx.x * 4;
    #pragma unroll
    for (int j = 0; j < 4; j++)
        if (base + j < NN) ptr[base + j] += off;
    if (blockIdx.x == 0 && threadIdx.x == 0) ptr[NN] = NE;
}

// atomic-free: rank was recorded in k_hist.
__global__ __launch_bounds__(256) void k_fill(
    const int* __restrict__ src, const int* __restrict__ dst,
    const int* __restrict__ ptr_o, const int* __restrict__ ptr_i,
    const int* __restrict__ rank_o, const int* __restrict__ rank_i,
    int2* __restrict__ list_o, int2* __restrict__ list_i)
{
    int e = blockIdx.x * 256 + threadIdx.x;
    if (e < NE) {
        int s = src[e], t = dst[e];
        list_o[ptr_o[t] + rank_o[e]] = make_int2(e, s);
        list_i[ptr_i[s] + rank_i[e]] = make_int2(e, t);
    }
}

// One-time W -> bf16 fragment-linear layout. Unit u = (kc_g*4 + q)*128 + c
// holds the short8 B-fragment (col c, k = (kc_g%4)*32 + q*8 .. +8).
__global__ __launch_bounds__(256) void k_wprep(
    const float* __restrict__ W0, const float* __restrict__ W1, const float* __restrict__ W2,
    unsigned short* __restrict__ Wbf)
{
    int gid = blockIdx.x * 256 + threadIdx.x;     // 0..12287
    int m = gid >> 12;
    int rem = gid & 4095;
    int c = rem >> 5;
    int k0 = (rem & 31) * 4;
    const float* W = (m == 0) ? W0 : (m == 1) ? W1 : W2;
    float4 v = *(const float4*)&W[c * DD + k0];
    int kL = k0 >> 5;
    int q = (k0 >> 3) & 3;
    int off = k0 & 7;
    int unit = ((m * 4 + kL) * 4 + q) * 128 + c;
    ushort4 o = { f2bf(v.x), f2bf(v.y), f2bf(v.z), f2bf(v.w) };
    *(ushort4*)&Wbf[unit * 8 + off] = o;
}

// ---------- fused gather + MFMA GEMM ----------
// Block = 32 nodes. Gather: 4 waves x 16 (node,dir) tasks; batched-readlane
// edge loop (8 edges in flight); results -> swizzled LDS A-tile as bf16
// (cols 0..255); node rows staged to cols 256..383. GEMM: K-loop over 12
// chunks; A frags via swizzled ds_read_b128 (conflict-free); B frags loaded
// per-wave straight from fragment-linear Wbf in global (L2-resident) -> no
// s_b, no inner barriers. LDS = 24KB -> 6 blocks/CU (75% occupancy).
__global__ __launch_bounds__(256) void k_gg(
    const float* __restrict__ node, const float* __restrict__ edge,
    const int* __restrict__ ptr_o, const int* __restrict__ ptr_i,
    const int2* __restrict__ list_o, const int2* __restrict__ list_i,
    const unsigned short* __restrict__ Wbf,
    const float* __restrict__ b0, const float* __restrict__ b1, const float* __restrict__ b2,
    float* __restrict__ h, float* __restrict__ col_sum, float* __restrict__ col_sumsq)
{
    __shared__ __align__(16) unsigned short s_x[32 * 384];   // 24576 B, 16B-aligned
    char* sx = (char*)s_x;

    const int tid = threadIdx.x;
    const int n0 = blockIdx.x * 32;
    const int w  = tid >> 6;
    const int l  = tid & 63;
    const int half = l >> 5;
    const int li32 = l & 31;
    const int q  = l >> 4;
    const int li = l & 15;
    const int srow = tid >> 3;      // 0..31
    const int skq  = tid & 7;       // float4 slot 0..7

    // ---- stage node rows into A cols 256..383 (swizzled) ----
    #pragma unroll
    for (int c4 = 0; c4 < 4; c4++) {
        float4 v = *(const float4*)&node[(size_t)(n0 + srow) * DD + c4 * 32 + 4 * skq];
        ushort4 o = { f2bf(v.x), f2bf(v.y), f2bf(v.z), f2bf(v.w) };
        *(ushort4*)(sx + AX(srow, 512 + c4 * 64 + skq * 8)) = o;
    }

    // ---- gather: 16 (node,dir) tasks per wave -> s_x cols 0..255 ----
    for (int it = 0; it < 16; it++) {
        int tsk = w * 16 + it;
        int dirI = tsk >= 32;
        int nl = tsk & 31;
        int n = n0 + nl;
        const int* ptr   = dirI ? ptr_i  : ptr_o;
        const int2* list = dirI ? list_i : list_o;

        int p0 = ptr[n], p1 = ptr[n + 1];
        int deg = p1 - p0;
        int degc = (deg < 64) ? deg : 64;

        int2 eu = make_int2(0, 0);
        if (l < degc) eu = list[p0 + l];

        float4_t a = {0.f, 0.f, 0.f, 0.f};
        for (int t = 0; t < degc; t += 8) {
            int es[4], us[4];
            float ms[4];
            float4_t xs[4], ys[4];
            #pragma unroll
            for (int b = 0; b < 4; b++) {
                int i0 = t + 2 * b;
                int l0 = (i0     < 64) ? i0     : 0;   // wave-uniform clamp
                int l1 = (i0 + 1 < 64) ? i0 + 1 : 0;
                int e0 = __builtin_amdgcn_readlane(eu.x, l0);
                int u0 = __builtin_amdgcn_readlane(eu.y, l0);
                int e1 = __builtin_amdgcn_readlane(eu.x, l1);
                int u1 = __builtin_amdgcn_readlane(eu.y, l1);
                es[b] = half ? e1 : e0;
                us[b] = half ? u1 : u0;
                ms[b] = (i0 + half < degc) ? 1.0f : 0.0f;
            }
            #pragma unroll
            for (int b = 0; b < 4; b++) {
                xs[b] = *((const float4_t*)(node + (size_t)us[b] * DD) + li32);
                ys[b] = *((const float4_t*)(edge + (size_t)es[b] * DD) + li32);
            }
            #pragma unroll
            for (int b = 0; b < 4; b++) {
                #pragma unroll
                for (int c = 0; c < 4; c++)
                    a[c] = fmaf(xs[b][c] - ys[b][c], ms[b], a[c]);
            }
        }
        // rare deg > 64 tail
        for (int j = p0 + 64 + half; j < p1; j += 2) {
            int2 t2 = list[j];
            float4_t x = *((const float4_t*)(node + (size_t)t2.y * DD) + li32);
            float4_t y = *((const float4_t*)(edge + (size_t)t2.x * DD) + li32);
            a += x - y;
        }
        float4_t bsh;
        #pragma unroll
        for (int c = 0; c < 4; c++) bsh[c] = __shfl_xor(a[c], 32);
        a += bsh;
        float inv = (deg > 0) ? 1.0f / (float)deg : 0.0f;
        a *= inv;
        if (half == 0) {
            ushort4 o = { f2bf(a[0]), f2bf(a[1]), f2bf(a[2]), f2bf(a[3]) };
            *(ushort4*)(sx + AX(nl, dirI * 256 + li32 * 8)) = o;
        }
    }
    __syncthreads();

    // ---- GEMM K-loop: 12 chunks of 32, barrier-free ----
    float4_t acc[2][2];
    #pragma unroll
    for (int i = 0; i < 2; i++)
        #pragma unroll
        for (int j = 0; j < 2; j++) acc[i][j] = (float4_t){0.f, 0.f, 0.f, 0.f};

    const short8_t* Wf = (const short8_t*)Wbf;
    #pragma unroll 4
    for (int kc = 0; kc < 12; kc++) {
        short8_t af0 = *(const short8_t*)(sx + AX(li,      kc * 64 + q * 16));
        short8_t af1 = *(const short8_t*)(sx + AX(16 + li, kc * 64 + q * 16));
        short8_t bf0 = Wf[(kc * 4 + q) * 128 + 32 * w + li];
        short8_t bf1 = Wf[(kc * 4 + q) * 128 + 32 * w + 16 + li];

        acc[0][0] = __builtin_amdgcn_mfma_f32_16x16x32_bf16(af0, bf0, acc[0][0], 0, 0, 0);
        acc[0][1] = __builtin_amdgcn_mfma_f32_16x16x32_bf16(af0, bf1, acc[0][1], 0, 0, 0);
        acc[1][0] = __builtin_amdgcn_mfma_f32_16x16x32_bf16(af1, bf0, acc[1][0], 0, 0, 0);
        acc[1][1] = __builtin_amdgcn_mfma_f32_16x16x32_bf16(af1, bf1, acc[1][1], 0, 0, 0);
    }
    __syncthreads();   // all frag reads done before s_red overlays s_x
    float* s_red = (float*)s_x;   // 4096 B <= 24576 B

    // epilogue: bias, /3, store h, BN partials
    // C/D layout: col = lane&15 (within 16-tile), row = (lane>>4)*4 + reg
    const float third = 1.0f / 3.0f;
    #pragma unroll
    for (int j = 0; j < 2; j++) {
        int c = 32 * w + 16 * j + li;
        float bsum = b0[c] + b1[c] + b2[c];
        float s = 0.f, sq = 0.f;
        #pragma unroll
        for (int i = 0; i < 2; i++)
            #pragma unroll
            for (int reg = 0; reg < 4; reg++) {
                int r = n0 + 16 * i + q * 4 + reg;
                float v = (acc[i][j][reg] + bsum) * third;
                h[(size_t)r * DD + c] = v;
                s += v; sq += v * v;
            }
        s_red[q * 128 + c]       = s;
        s_red[512 + q * 128 + c] = sq;
    }
    __syncthreads();
    if (tid < 128) {
        float s = 0.f, sq = 0.f;
        #pragma unroll
        for (int r4 = 0; r4 < 4; r4++) {
            s  += s_red[r4 * 128 + tid];
            sq += s_red[512 + r4 * 128 + tid];
        }
        unsafeAtomicAdd(col_sum + tid, s);
        unsafeAtomicAdd(col_sumsq + tid, sq);
    }
}

// k_norm with k_stats folded in: each block recomputes the 128 scale/bias
// values from the atomic-summed column stats (1 KB L2-broadcast read).
__global__ __launch_bounds__(256) void k_norm(const float* __restrict__ h,
        const float* __restrict__ col_sum, const float* __restrict__ col_sumsq,
        const float* __restrict__ gamma, const float* __restrict__ beta,
        float* __restrict__ out)
{
    __shared__ float ssc[128], sbs[128];
    int tid = threadIdx.x;
    if (tid < 128) {
        float mu  = col_sum[tid]   * (1.0f / NN);
        float var = col_sumsq[tid] * (1.0f / NN) - mu * mu;
        var = fmaxf(var, 0.0f);
        float rs = rsqrtf(var + 1e-5f);
        float g = gamma[tid];
        ssc[tid] = rs * g;
        sbs[tid] = beta[tid] - mu * rs * g;
    }
    __syncthreads();
    size_t base = ((size_t)blockIdx.x * 256 + tid) * 4;
    float4 v = *(const float4*)(h + base);
    int j = (int)(base & 127);
    float4 o;
    o.x = fmaf(v.x, ssc[j],     sbs[j]);
    o.y = fmaf(v.y, ssc[j + 1], sbs[j + 1]);
    o.z = fmaf(v.z, ssc[j + 2], sbs[j + 2]);
    o.w = fmaf(v.w, ssc[j + 3], sbs[j + 3]);
    *(float4*)(out + base) = o;
}

extern "C" void kernel_launch(void* const* d_in, const int* in_sizes, int n_in,
                              void* d_out, int out_size, void* d_ws, size_t ws_size,
                              hipStream_t stream)
{
    const float* node  = (const float*)d_in[0];
    const float* edge  = (const float*)d_in[1];
    const float* W0    = (const float*)d_in[2];
    const float* b0    = (const float*)d_in[3];
    const float* W1    = (const float*)d_in[4];
    const float* b1    = (const float*)d_in[5];
    const float* W2    = (const float*)d_in[6];
    const float* b2    = (const float*)d_in[7];
    const float* gamma = (const float*)d_in[8];
    const float* beta  = (const float*)d_in[9];
    const int* src = (const int*)d_in[10];
    const int* dst = (const int*)d_in[11];
    float* out = (float*)d_out;

    const size_t NB = (size_t)NN * DD;
    float* h = (float*)d_ws;               // NB floats (51,200,000 B, 16B-aligned)
    // Wbf directly after h: offset mod 16 == 0 -> legal short8 (16B) loads.
    unsigned short* Wbf = (unsigned short*)(h + NB);   // 3*16*4*128*8 = 49152 shorts (98304 B)
    // ---- zeroed region ----
    int* cnt_o = (int*)(Wbf + 49152);      // NN
    int* cnt_i = cnt_o + NN;               // NN
    float* col_sum   = (float*)(cnt_i + NN);   // 128
    float* col_sumsq = col_sum + DD;           // 128
    // ---- end zeroed region ----
    int* ptr_o = (int*)(col_sumsq + DD);   // NN+1
    int* ptr_i = ptr_o + (NN + 1);         // NN+1
    int* bsum  = ptr_i + (NN + 1);         // 2*128
    int* rank_o = bsum + 256;              // NE
    int* rank_i = rank_o + NE;             // NE
    int2* list_o = (int2*)(rank_i + NE);   // NE int2 (offset mod 8 == 0)
    int2* list_i = list_o + NE;            // NE int2

    size_t zbytes = (size_t)(2 * NN + 2 * DD) * sizeof(int);
    hipMemsetAsync(cnt_o, 0, zbytes, stream);

    int egrid = (NE + 255) / 256;
    k_wprep<<<48, 256, 0, stream>>>(W0, W1, W2, Wbf);
    k_hist <<<egrid, 256, 0, stream>>>(src, dst, cnt_o, cnt_i, rank_o, rank_i);
    k_scanA<<<dim3(NBLK, 2), 256, 0, stream>>>(cnt_o, cnt_i, ptr_o, ptr_i, bsum);
    k_scanB<<<dim3(1, 2), 128, 0, stream>>>(bsum);
    k_scanC<<<dim3(NBLK, 2), 256, 0, stream>>>(ptr_o, ptr_i, bsum);
    k_fill <<<egrid, 256, 0, stream>>>(src, dst, ptr_o, ptr_i, rank_o, rank_i, list_o, list_i);
    k_gg  <<<NN / 32, 256, 0, stream>>>(node, edge, ptr_o, ptr_i, list_o, list_i,
                                        Wbf, b0, b1, b2, h, col_sum, col_sumsq);
    k_norm<<<(NN * DD) / 1024, 256, 0, stream>>>(h, col_sum, col_sumsq, gamma, beta, out);
}